// Round 3
// baseline (1568.236 us; speedup 1.0000x reference)
//
#include <hip/hip_runtime.h>
#include <math.h>

#define NROWS 16384
#define DDIM  2048
#define EEXP  64
#define RB    16               // rows per block
#define KD    32               // d per chunk
#define NCHUNK (DDIM / KD)     // 64
#define XSTR  (KD + 4)         // padded x-tile stride (dwords) -> conflict-free b128 reads

__global__ __launch_bounds__(256, 4)
void router_kernel(const float* __restrict__ x,
                   const float* __restrict__ W,
                   const float* __restrict__ b,
                   float* __restrict__ mask_out,
                   float* __restrict__ idx_out) {
    __shared__ float xt[2][RB * XSTR];     // 2 x 2.25 KB
    __shared__ float wt[2][KD * EEXP];     // 2 x 8 KB

    const int tid  = threadIdx.x;
    const int lane = tid & 63;
    const int wave = __builtin_amdgcn_readfirstlane(tid >> 6);
    const int eg   = lane & 15;            // expert group: experts 4eg..4eg+3
    const int rg   = lane >> 4;            // row within wave's 4-row micro-tile
    const int lrow = wave * 4 + rg;        // row within block, 0..15
    const int row0 = blockIdx.x * RB;

    // staging coords: thread t stages row (t>>4), d-pair 2*(t&15) of x (coalesced 128B/row)
    const int srow = tid >> 4;
    const int sd   = (tid & 15) * 2;
    const float*  xsrc = x + (size_t)(row0 + srow) * DDIM + sd;
    const float4* wsrc = (const float4*)W;   // chunk c: float4 #(c*512 + tid) and +256

    float2 acc[4] = {{0.f,0.f},{0.f,0.f},{0.f,0.f},{0.f,0.f}};

    // prologue: stage chunk 0 into buf 0 (vector loads, coalesced)
    {
        float2 xs = *(const float2*)xsrc;
        float4 wa = wsrc[tid];
        float4 wb = wsrc[tid + 256];
        xt[0][srow * XSTR + sd]     = xs.x;
        xt[0][srow * XSTR + sd + 1] = xs.y;
        ((float4*)wt[0])[tid]       = wa;
        ((float4*)wt[0])[tid + 256] = wb;
    }

#pragma unroll 1
    for (int c = 0; c < NCHUNK; ++c) {
        const int buf = c & 1;
        const bool more = (c + 1) < NCHUNK;
        float2 nxs; float4 nwa, nwb;
        if (more) {   // issue next-chunk global loads early; vmcnt covered by compute
            nxs = *(const float2*)(xsrc + (size_t)(c + 1) * KD);
            nwa = wsrc[(size_t)(c + 1) * 512 + tid];
            nwb = wsrc[(size_t)(c + 1) * 512 + tid + 256];
        }
        __syncthreads();   // buf[c&1] ready for all waves

        const float* xp = &xt[buf][lrow * XSTR];
        const float* wp = wt[buf];
#pragma unroll
        for (int d = 0; d < KD; d += 4) {
            float4 xv = *(const float4*)(xp + d);                        // 4-addr broadcast
            float4 w0 = *(const float4*)(wp + (d + 0) * EEXP + 4 * eg);  // 2-way, free
            float4 w1 = *(const float4*)(wp + (d + 1) * EEXP + 4 * eg);
            float4 w2 = *(const float4*)(wp + (d + 2) * EEXP + 4 * eg);
            float4 w3 = *(const float4*)(wp + (d + 3) * EEXP + 4 * eg);
            const float* w0f = (const float*)&w0;
            const float* w1f = (const float*)&w1;
            const float* w2f = (const float*)&w2;
            const float* w3f = (const float*)&w3;
#pragma unroll
            for (int j = 0; j < 4; ++j) {   // even-d in .x, odd-d in .y (pk_fma-friendly)
                acc[j].x = fmaf(xv.x, w0f[j], acc[j].x);
                acc[j].y = fmaf(xv.y, w1f[j], acc[j].y);
                acc[j].x = fmaf(xv.z, w2f[j], acc[j].x);
                acc[j].y = fmaf(xv.w, w3f[j], acc[j].y);
            }
        }

        if (more) {   // write next chunk into the other buffer (safe: all passed this iter's barrier)
            const int nbuf = buf ^ 1;
            xt[nbuf][srow * XSTR + sd]     = nxs.x;
            xt[nbuf][srow * XSTR + sd + 1] = nxs.y;
            ((float4*)wt[nbuf])[tid]       = nwa;
            ((float4*)wt[nbuf])[tid + 256] = nwb;
        }
    }

    // ---- epilogue: softmax + top-2 across the 16-lane row group ----
    float4 bias = *(const float4*)(b + 4 * eg);
    const float* bf = (const float*)&bias;
    float logit[4];
#pragma unroll
    for (int j = 0; j < 4; ++j) logit[j] = acc[j].x + acc[j].y + bf[j];

    float m = fmaxf(fmaxf(logit[0], logit[1]), fmaxf(logit[2], logit[3]));
#pragma unroll
    for (int off = 8; off >= 1; off >>= 1)
        m = fmaxf(m, __shfl_xor(m, off));

    float ex[4], s = 0.f;
#pragma unroll
    for (int j = 0; j < 4; ++j) { ex[j] = __expf(logit[j] - m); s += ex[j]; }
#pragma unroll
    for (int off = 8; off >= 1; off >>= 1)
        s += __shfl_xor(s, off);
    const float inv = 1.0f / s;

    // top-1 (ties -> lowest index, matches lax.top_k)
    float v1 = logit[0]; int i1 = 4 * eg;
#pragma unroll
    for (int j = 1; j < 4; ++j)
        if (logit[j] > v1) { v1 = logit[j]; i1 = 4 * eg + j; }
#pragma unroll
    for (int off = 8; off >= 1; off >>= 1) {
        float ov = __shfl_xor(v1, off);
        int   oi = __shfl_xor(i1, off);
        if (ov > v1 || (ov == v1 && oi < i1)) { v1 = ov; i1 = oi; }
    }
    // top-2
    float v2 = -INFINITY; int i2 = EEXP;
#pragma unroll
    for (int j = 0; j < 4; ++j) {
        const int e = 4 * eg + j;
        const float lv = (e == i1) ? -INFINITY : logit[j];
        if (lv > v2 || (lv == v2 && e < i2)) { v2 = lv; i2 = e; }
    }
#pragma unroll
    for (int off = 8; off >= 1; off >>= 1) {
        float ov = __shfl_xor(v2, off);
        int   oi = __shfl_xor(i2, off);
        if (ov > v2 || (ov == v2 && oi < i2)) { v2 = ov; i2 = oi; }
    }

    const int grow = row0 + lrow;
    float4 ov4; float* ovf = (float*)&ov4;
#pragma unroll
    for (int j = 0; j < 4; ++j) {
        const int e = 4 * eg + j;
        ovf[j] = (e == i1 || e == i2) ? ex[j] * inv : 0.0f;
    }
    *(float4*)(mask_out + (size_t)grow * EEXP + 4 * eg) = ov4;  // 16 lanes -> 256B/row
    if (eg == 0) {
        idx_out[grow * 2 + 0] = (float)i1;
        idx_out[grow * 2 + 1] = (float)i2;
    }
}

extern "C" void kernel_launch(void* const* d_in, const int* in_sizes, int n_in,
                              void* d_out, int out_size, void* d_ws, size_t ws_size,
                              hipStream_t stream) {
    const float* x = (const float*)d_in[0];
    const float* W = (const float*)d_in[1];
    const float* b = (const float*)d_in[2];
    float* mask_out = (float*)d_out;
    float* idx_out  = mask_out + (size_t)NROWS * EEXP;

    dim3 grid(NROWS / RB);    // 1024 blocks -> 4 blocks/CU
    dim3 block(256);
    router_kernel<<<grid, block, 0, stream>>>(x, W, b, mask_out, idx_out);
}

// Round 4
// 329.424 us; speedup vs baseline: 4.7605x; 4.7605x over previous
//
#include <hip/hip_runtime.h>
#include <math.h>

#define NROWS 16384
#define DDIM  2048
#define EEXP  64
#define RB    16                 // rows per block
#define NW    4                  // waves per block; D split 4 ways
#define DSL   (DDIM / NW)        // 512 d per wave
#define NMICRO (DSL / 4)         // 128 micro-steps of 4 d

// 16 FMAs: one d-value applied to 2 rows x 8 experts
#define FMA_D(xa, xb, wl, wh)                                   \
    acc0[0] = fmaf(xa, wl.x, acc0[0]);                          \
    acc0[1] = fmaf(xa, wl.y, acc0[1]);                          \
    acc0[2] = fmaf(xa, wl.z, acc0[2]);                          \
    acc0[3] = fmaf(xa, wl.w, acc0[3]);                          \
    acc0[4] = fmaf(xa, wh.x, acc0[4]);                          \
    acc0[5] = fmaf(xa, wh.y, acc0[5]);                          \
    acc0[6] = fmaf(xa, wh.z, acc0[6]);                          \
    acc0[7] = fmaf(xa, wh.w, acc0[7]);                          \
    acc1[0] = fmaf(xb, wl.x, acc1[0]);                          \
    acc1[1] = fmaf(xb, wl.y, acc1[1]);                          \
    acc1[2] = fmaf(xb, wl.z, acc1[2]);                          \
    acc1[3] = fmaf(xb, wl.w, acc1[3]);                          \
    acc1[4] = fmaf(xb, wh.x, acc1[4]);                          \
    acc1[5] = fmaf(xb, wh.y, acc1[5]);                          \
    acc1[6] = fmaf(xb, wh.z, acc1[6]);                          \
    acc1[7] = fmaf(xb, wh.w, acc1[7]);

__global__ __launch_bounds__(256, 4)
void router_kernel(const float* __restrict__ x,
                   const float* __restrict__ W,
                   const float* __restrict__ bias_v,
                   float* __restrict__ mask_out,
                   float* __restrict__ idx_out) {
    __shared__ float part[NW][RB][EEXP];   // 16 KB

    const int tid  = threadIdx.x;
    const int lane = tid & 63;
    const int wave = __builtin_amdgcn_readfirstlane(tid >> 6);
    const int eg   = lane & 7;    // expert group: experts 8*eg .. 8*eg+7
    const int rg   = lane >> 3;   // row group: rows rg and rg+8
    const int row0 = blockIdx.x * RB;
    const int dbase = wave * DSL;

    const float4* x0 = (const float4*)(x + (size_t)(row0 + rg) * DDIM + dbase);
    const float4* x1 = (const float4*)(x + (size_t)(row0 + rg + 8) * DDIM + dbase);
    // per d: lo half = wb[d*16], hi half = wb[d*16 + 1]  (float4 units)
    const float4* wb = (const float4*)(W + (size_t)dbase * EEXP + eg * 8);

    float acc0[8] = {0.f,0.f,0.f,0.f,0.f,0.f,0.f,0.f};
    float acc1[8] = {0.f,0.f,0.f,0.f,0.f,0.f,0.f,0.f};

    // current micro-step registers (prologue load)
    float4 cx0 = x0[0];
    float4 cx1 = x1[0];
    float4 cw0l = wb[0],  cw0h = wb[1];
    float4 cw1l = wb[16], cw1h = wb[17];
    float4 cw2l = wb[32], cw2h = wb[33];
    float4 cw3l = wb[48], cw3h = wb[49];
    // next-step registers (init'd so last-iter copy isn't UB)
    float4 nx0 = cx0, nx1 = cx1;
    float4 nw0l = cw0l, nw0h = cw0h, nw1l = cw1l, nw1h = cw1h;
    float4 nw2l = cw2l, nw2h = cw2h, nw3l = cw3l, nw3h = cw3h;

#pragma unroll 1
    for (int i = 0; i < NMICRO; ++i) {
        if (i + 1 < NMICRO) {           // prefetch next 4-d micro-step
            nx0 = x0[i + 1];
            nx1 = x1[i + 1];
            const float4* wp = wb + (size_t)(i + 1) * 64;
            nw0l = wp[0];  nw0h = wp[1];
            nw1l = wp[16]; nw1h = wp[17];
            nw2l = wp[32]; nw2h = wp[33];
            nw3l = wp[48]; nw3h = wp[49];
        }
        FMA_D(cx0.x, cx1.x, cw0l, cw0h)
        FMA_D(cx0.y, cx1.y, cw1l, cw1h)
        FMA_D(cx0.z, cx1.z, cw2l, cw2h)
        FMA_D(cx0.w, cx1.w, cw3l, cw3h)
        cx0 = nx0; cx1 = nx1;
        cw0l = nw0l; cw0h = nw0h; cw1l = nw1l; cw1h = nw1h;
        cw2l = nw2l; cw2h = nw2h; cw3l = nw3l; cw3h = nw3h;
    }

    // dump partials (constant indices only; contiguous 8 floats per row)
#pragma unroll
    for (int j = 0; j < 8; ++j) {
        part[wave][rg][eg * 8 + j]     = acc0[j];
        part[wave][rg + 8][eg * 8 + j] = acc1[j];
    }
    __syncthreads();

    // epilogue: lane-per-expert, 4 rows per wave (R1-verified code path)
    const float bias = bias_v[lane];
#pragma unroll
    for (int rr = 0; rr < RB / NW; ++rr) {
        const int r   = wave * (RB / NW) + rr;
        const int row = row0 + r;
        float logit = part[0][r][lane] + part[1][r][lane]
                    + part[2][r][lane] + part[3][r][lane] + bias;

        float m = logit;
#pragma unroll
        for (int off = 32; off >= 1; off >>= 1)
            m = fmaxf(m, __shfl_xor(m, off));
        float ex = __expf(logit - m);
        float s = ex;
#pragma unroll
        for (int off = 32; off >= 1; off >>= 1)
            s += __shfl_xor(s, off);
        float gate = ex / s;

        float v1 = logit; int i1 = lane;
#pragma unroll
        for (int off = 32; off >= 1; off >>= 1) {
            float ov = __shfl_xor(v1, off);
            int   oi = __shfl_xor(i1, off);
            if (ov > v1 || (ov == v1 && oi < i1)) { v1 = ov; i1 = oi; }
        }
        float v2 = (lane == i1) ? -INFINITY : logit; int i2 = lane;
#pragma unroll
        for (int off = 32; off >= 1; off >>= 1) {
            float ov = __shfl_xor(v2, off);
            int   oi = __shfl_xor(i2, off);
            if (ov > v2 || (ov == v2 && oi < i2)) { v2 = ov; i2 = oi; }
        }

        float outv = (lane == i1 || lane == i2) ? gate : 0.0f;
        mask_out[(size_t)row * EEXP + lane] = outv;
        if (lane == 0) {
            idx_out[row * 2 + 0] = (float)i1;
            idx_out[row * 2 + 1] = (float)i2;
        }
    }
}

extern "C" void kernel_launch(void* const* d_in, const int* in_sizes, int n_in,
                              void* d_out, int out_size, void* d_ws, size_t ws_size,
                              hipStream_t stream) {
    const float* x = (const float*)d_in[0];
    const float* W = (const float*)d_in[1];
    const float* b = (const float*)d_in[2];
    float* mask_out = (float*)d_out;
    float* idx_out  = mask_out + (size_t)NROWS * EEXP;

    dim3 grid(NROWS / RB);   // 1024 blocks -> 4 blocks/CU, 16 waves/CU
    dim3 block(256);
    router_kernel<<<grid, block, 0, stream>>>(x, W, b, mask_out, idx_out);
}

// Round 5
// 298.700 us; speedup vs baseline: 5.2502x; 1.1029x over previous
//
#include <hip/hip_runtime.h>
#include <math.h>

#define NROWS 16384
#define DDIM  2048
#define EEXP  64
#define RB    32                // rows per block
#define NW    8                 // waves per block; D split 8 ways
#define DSL   (DDIM / NW)       // 256 d per wave
#define NSTEP (DSL / 2)         // 128 steps of 2 d

// 8 FMAs: one x scalar against 8 experts (two float4 W halves)
#define FMA_ROW(a, xv, wl, wh)                         \
    a[0] = fmaf(xv, wl.x, a[0]);                       \
    a[1] = fmaf(xv, wl.y, a[1]);                       \
    a[2] = fmaf(xv, wl.z, a[2]);                       \
    a[3] = fmaf(xv, wl.w, a[3]);                       \
    a[4] = fmaf(xv, wh.x, a[4]);                       \
    a[5] = fmaf(xv, wh.y, a[5]);                       \
    a[6] = fmaf(xv, wh.z, a[6]);                       \
    a[7] = fmaf(xv, wh.w, a[7]);

// one 2-d step: 4 rows x 8 experts x 2 d = 64 FMAs
#define COMPUTE(X0, X1, X2, X3, W0L, W0H, W1L, W1H)    \
    FMA_ROW(acc0, X0.x, W0L, W0H)                      \
    FMA_ROW(acc1, X1.x, W0L, W0H)                      \
    FMA_ROW(acc2, X2.x, W0L, W0H)                      \
    FMA_ROW(acc3, X3.x, W0L, W0H)                      \
    FMA_ROW(acc0, X0.y, W1L, W1H)                      \
    FMA_ROW(acc1, X1.y, W1L, W1H)                      \
    FMA_ROW(acc2, X2.y, W1L, W1H)                      \
    FMA_ROW(acc3, X3.y, W1L, W1H)

// loads for step s: 4 x-float2 (distinct rows) + 4 W-float4 (2 d x 8 experts)
#define LOADS(s, X0, X1, X2, X3, W0L, W0H, W1L, W1H)   \
    X0 = xp0[s]; X1 = xp1[s]; X2 = xp2[s]; X3 = xp3[s];\
    W0L = wq[(size_t)(2*(s)) * 16];                    \
    W0H = wq[(size_t)(2*(s)) * 16 + 1];                \
    W1L = wq[(size_t)(2*(s)+1) * 16];                  \
    W1H = wq[(size_t)(2*(s)+1) * 16 + 1];

__global__ __launch_bounds__(512, 4)
void router_kernel(const float* __restrict__ x,
                   const float* __restrict__ W,
                   const float* __restrict__ bias_v,
                   float* __restrict__ mask_out,
                   float* __restrict__ idx_out) {
    __shared__ float part[NW][RB][EEXP];   // 64 KB

    const int tid  = threadIdx.x;
    const int lane = tid & 63;
    const int wave = __builtin_amdgcn_readfirstlane(tid >> 6);
    const int er   = lane & 7;     // expert octet: experts 8*er .. 8*er+7
    const int rg   = lane >> 3;    // row quad: rows 4*rg .. 4*rg+3
    const int row0 = blockIdx.x * RB;
    const int dbase = wave * DSL;

    const float2* xp0 = (const float2*)(x + (size_t)(row0 + rg*4 + 0) * DDIM + dbase);
    const float2* xp1 = (const float2*)(x + (size_t)(row0 + rg*4 + 1) * DDIM + dbase);
    const float2* xp2 = (const float2*)(x + (size_t)(row0 + rg*4 + 2) * DDIM + dbase);
    const float2* xp3 = (const float2*)(x + (size_t)(row0 + rg*4 + 3) * DDIM + dbase);
    // W row d = 16 float4; lane er takes float4s (er*2) and (er*2+1)
    const float4* wq = (const float4*)W + (size_t)dbase * 16 + er * 2;

    float acc0[8] = {0,0,0,0,0,0,0,0};
    float acc1[8] = {0,0,0,0,0,0,0,0};
    float acc2[8] = {0,0,0,0,0,0,0,0};
    float acc3[8] = {0,0,0,0,0,0,0,0};

    float2 ax0, ax1, ax2, ax3; float4 aw0l, aw0h, aw1l, aw1h;   // buffer A
    float2 bx0, bx1, bx2, bx3; float4 bw0l, bw0h, bw1l, bw1h;   // buffer B

    LOADS(0, ax0, ax1, ax2, ax3, aw0l, aw0h, aw1l, aw1h)

#pragma unroll 1
    for (int s = 0; s < NSTEP; s += 2) {
        LOADS(s + 1, bx0, bx1, bx2, bx3, bw0l, bw0h, bw1l, bw1h)   // always valid (NSTEP even)
        COMPUTE(ax0, ax1, ax2, ax3, aw0l, aw0h, aw1l, aw1h)
        if (s + 2 < NSTEP) {
            LOADS(s + 2, ax0, ax1, ax2, ax3, aw0l, aw0h, aw1l, aw1h)
        }
        COMPUTE(bx0, bx1, bx2, bx3, bw0l, bw0h, bw1l, bw1h)
    }

    // partials -> LDS (constant indices only; 8 contiguous floats per row)
#pragma unroll
    for (int e = 0; e < 8; ++e) {
        part[wave][rg*4 + 0][er*8 + e] = acc0[e];
        part[wave][rg*4 + 1][er*8 + e] = acc1[e];
        part[wave][rg*4 + 2][er*8 + e] = acc2[e];
        part[wave][rg*4 + 3][er*8 + e] = acc3[e];
    }
    __syncthreads();

    // epilogue: lane-per-expert softmax + top-2 (verified path), 4 rows/wave
    const float bias = bias_v[lane];
#pragma unroll
    for (int rr = 0; rr < RB / NW; ++rr) {
        const int r   = wave * (RB / NW) + rr;
        const int row = row0 + r;
        float logit = bias;
#pragma unroll
        for (int p = 0; p < NW; ++p) logit += part[p][r][lane];

        float m = logit;
#pragma unroll
        for (int off = 32; off >= 1; off >>= 1)
            m = fmaxf(m, __shfl_xor(m, off));
        float ex = __expf(logit - m);
        float s = ex;
#pragma unroll
        for (int off = 32; off >= 1; off >>= 1)
            s += __shfl_xor(s, off);
        float gate = ex / s;

        float v1 = logit; int i1 = lane;
#pragma unroll
        for (int off = 32; off >= 1; off >>= 1) {
            float ov = __shfl_xor(v1, off);
            int   oi = __shfl_xor(i1, off);
            if (ov > v1 || (ov == v1 && oi < i1)) { v1 = ov; i1 = oi; }
        }
        float v2 = (lane == i1) ? -INFINITY : logit; int i2 = lane;
#pragma unroll
        for (int off = 32; off >= 1; off >>= 1) {
            float ov = __shfl_xor(v2, off);
            int   oi = __shfl_xor(i2, off);
            if (ov > v2 || (ov == v2 && oi < i2)) { v2 = ov; i2 = oi; }
        }

        float outv = (lane == i1 || lane == i2) ? gate : 0.0f;
        mask_out[(size_t)row * EEXP + lane] = outv;
        if (lane == 0) {
            idx_out[row * 2 + 0] = (float)i1;
            idx_out[row * 2 + 1] = (float)i2;
        }
    }
}

extern "C" void kernel_launch(void* const* d_in, const int* in_sizes, int n_in,
                              void* d_out, int out_size, void* d_ws, size_t ws_size,
                              hipStream_t stream) {
    const float* x = (const float*)d_in[0];
    const float* W = (const float*)d_in[1];
    const float* b = (const float*)d_in[2];
    float* mask_out = (float*)d_out;
    float* idx_out  = mask_out + (size_t)NROWS * EEXP;

    dim3 grid(NROWS / RB);   // 512 blocks -> 2 blocks/CU, 16 waves/CU
    dim3 block(512);         // 8 waves, D split 8 ways
    router_kernel<<<grid, block, 0, stream>>>(x, W, b, mask_out, idx_out);
}

// Round 6
// 214.985 us; speedup vs baseline: 7.2946x; 1.3894x over previous
//
#include <hip/hip_runtime.h>
#include <math.h>

#define NROWS 16384
#define DDIM  2048
#define EEXP  64
#define RB    64               // rows per block
#define KD    64               // d per LDS chunk
#define NCHUNK (DDIM / KD)     // 32
#define XSTR  68               // x tile row stride (dwords): pad 4 -> rg groups on distinct bank quads
#define WSTR  64               // w tile row stride
#define PSTR  66               // epilogue partial row stride

// smem float offsets: x bufs [2][64][68] = 8704; w bufs [2][64][64] = 8192; total 16896 (67.6 KB)
#define XOFF(b) ((b) * 4352)
#define WOFF(b) (8704 + (b) * 4096)

// 32 FMAs: one row's 4 d-values (xv float4) against 8 experts (wl*/wh* per d)
#define ROW_FMA(i, XV)                                                        \
    acc[i][0]=fmaf(XV.x,wl0.x,acc[i][0]); acc[i][1]=fmaf(XV.x,wl0.y,acc[i][1]); \
    acc[i][2]=fmaf(XV.x,wl0.z,acc[i][2]); acc[i][3]=fmaf(XV.x,wl0.w,acc[i][3]); \
    acc[i][4]=fmaf(XV.x,wh0.x,acc[i][4]); acc[i][5]=fmaf(XV.x,wh0.y,acc[i][5]); \
    acc[i][6]=fmaf(XV.x,wh0.z,acc[i][6]); acc[i][7]=fmaf(XV.x,wh0.w,acc[i][7]); \
    acc[i][0]=fmaf(XV.y,wl1.x,acc[i][0]); acc[i][1]=fmaf(XV.y,wl1.y,acc[i][1]); \
    acc[i][2]=fmaf(XV.y,wl1.z,acc[i][2]); acc[i][3]=fmaf(XV.y,wl1.w,acc[i][3]); \
    acc[i][4]=fmaf(XV.y,wh1.x,acc[i][4]); acc[i][5]=fmaf(XV.y,wh1.y,acc[i][5]); \
    acc[i][6]=fmaf(XV.y,wh1.z,acc[i][6]); acc[i][7]=fmaf(XV.y,wh1.w,acc[i][7]); \
    acc[i][0]=fmaf(XV.z,wl2.x,acc[i][0]); acc[i][1]=fmaf(XV.z,wl2.y,acc[i][1]); \
    acc[i][2]=fmaf(XV.z,wl2.z,acc[i][2]); acc[i][3]=fmaf(XV.z,wl2.w,acc[i][3]); \
    acc[i][4]=fmaf(XV.z,wh2.x,acc[i][4]); acc[i][5]=fmaf(XV.z,wh2.y,acc[i][5]); \
    acc[i][6]=fmaf(XV.z,wh2.z,acc[i][6]); acc[i][7]=fmaf(XV.z,wh2.w,acc[i][7]); \
    acc[i][0]=fmaf(XV.w,wl3.x,acc[i][0]); acc[i][1]=fmaf(XV.w,wl3.y,acc[i][1]); \
    acc[i][2]=fmaf(XV.w,wl3.z,acc[i][2]); acc[i][3]=fmaf(XV.w,wl3.w,acc[i][3]); \
    acc[i][4]=fmaf(XV.w,wh3.x,acc[i][4]); acc[i][5]=fmaf(XV.w,wh3.y,acc[i][5]); \
    acc[i][6]=fmaf(XV.w,wh3.z,acc[i][6]); acc[i][7]=fmaf(XV.w,wh3.w,acc[i][7]);

// one 4-d group: 8 x b128 (8 rows) + 8 w b128 (4d x 8e) + 256 FMAs
#define GROUP(d0)                                                             \
    {                                                                         \
        float4 xv0 = *(const float4*)(xb + 0*544 + (d0));                     \
        float4 xv1 = *(const float4*)(xb + 1*544 + (d0));                     \
        float4 xv2 = *(const float4*)(xb + 2*544 + (d0));                     \
        float4 xv3 = *(const float4*)(xb + 3*544 + (d0));                     \
        float4 xv4 = *(const float4*)(xb + 4*544 + (d0));                     \
        float4 xv5 = *(const float4*)(xb + 5*544 + (d0));                     \
        float4 xv6 = *(const float4*)(xb + 6*544 + (d0));                     \
        float4 xv7 = *(const float4*)(xb + 7*544 + (d0));                     \
        float4 wl0 = *(const float4*)(wb + ((d0)+0)*WSTR);                    \
        float4 wh0 = *(const float4*)(wb + ((d0)+0)*WSTR + 4);                \
        float4 wl1 = *(const float4*)(wb + ((d0)+1)*WSTR);                    \
        float4 wh1 = *(const float4*)(wb + ((d0)+1)*WSTR + 4);                \
        float4 wl2 = *(const float4*)(wb + ((d0)+2)*WSTR);                    \
        float4 wh2 = *(const float4*)(wb + ((d0)+2)*WSTR + 4);                \
        float4 wl3 = *(const float4*)(wb + ((d0)+3)*WSTR);                    \
        float4 wh3 = *(const float4*)(wb + ((d0)+3)*WSTR + 4);                \
        ROW_FMA(0, xv0) ROW_FMA(1, xv1) ROW_FMA(2, xv2) ROW_FMA(3, xv3)       \
        ROW_FMA(4, xv4) ROW_FMA(5, xv5) ROW_FMA(6, xv6) ROW_FMA(7, xv7)       \
    }

__global__ __launch_bounds__(512, 2)
void router_kernel(const float* __restrict__ x,
                   const float* __restrict__ W,
                   const float* __restrict__ bias_v,
                   float* __restrict__ mask_out,
                   float* __restrict__ idx_out) {
    __shared__ __align__(16) float smem[16896];

    const int tid  = threadIdx.x;
    const int lane = tid & 63;
    const int wave = __builtin_amdgcn_readfirstlane(tid >> 6);
    const int eg   = lane & 7;     // experts 8*eg..8*eg+7
    const int rg   = lane >> 3;    // rows rg, rg+8, ..., rg+56
    const int row0 = blockIdx.x * RB;
    const int dw   = wave * 8;     // wave's d-slice within each chunk

    float acc[8][8];
#pragma unroll
    for (int i = 0; i < 8; ++i)
#pragma unroll
        for (int e = 0; e < 8; ++e) acc[i][e] = 0.0f;

    // ---- stage chunk 0 (each thread: 2 x-float4 + 2 w-float4) ----
    {
        const int f0 = tid, f1 = tid + 512;
        float4 vx0 = *(const float4*)(x + (size_t)(row0 + (f0 >> 4)) * DDIM + (f0 & 15) * 4);
        float4 vx1 = *(const float4*)(x + (size_t)(row0 + (f1 >> 4)) * DDIM + (f1 & 15) * 4);
        float4 vw0 = *(const float4*)(W + (size_t)(f0 >> 4) * EEXP + (f0 & 15) * 4);
        float4 vw1 = *(const float4*)(W + (size_t)(f1 >> 4) * EEXP + (f1 & 15) * 4);
        *(float4*)(smem + XOFF(0) + (f0 >> 4) * XSTR + (f0 & 15) * 4) = vx0;
        *(float4*)(smem + XOFF(0) + (f1 >> 4) * XSTR + (f1 & 15) * 4) = vx1;
        *(float4*)(smem + WOFF(0) + (f0 >> 4) * WSTR + (f0 & 15) * 4) = vw0;
        *(float4*)(smem + WOFF(0) + (f1 >> 4) * WSTR + (f1 & 15) * 4) = vw1;
    }

#pragma unroll 1
    for (int c = 0; c < NCHUNK; ++c) {
        const int buf = c & 1;
        const bool more = (c + 1) < NCHUNK;
        float4 vx0, vx1, vw0, vw1;
        if (more) {   // issue global loads for chunk c+1 (a full chunk of time to land)
            const int f0 = tid, f1 = tid + 512;
            const int cb = (c + 1) * KD;
            vx0 = *(const float4*)(x + (size_t)(row0 + (f0 >> 4)) * DDIM + cb + (f0 & 15) * 4);
            vx1 = *(const float4*)(x + (size_t)(row0 + (f1 >> 4)) * DDIM + cb + (f1 & 15) * 4);
            vw0 = *(const float4*)(W + (size_t)(cb + (f0 >> 4)) * EEXP + (f0 & 15) * 4);
            vw1 = *(const float4*)(W + (size_t)(cb + (f1 >> 4)) * EEXP + (f1 & 15) * 4);
        }
        __syncthreads();   // buf[c&1] fully staged for all waves

        const float* xb = smem + XOFF(buf) + rg * XSTR;      // row i at +544*i
        const float* wb = smem + WOFF(buf) + eg * 8;
        GROUP(dw)
        GROUP(dw + 4)

        if (more) {        // write chunk c+1 into the other buffer
            const int nb = buf ^ 1;
            const int f0 = tid, f1 = tid + 512;
            *(float4*)(smem + XOFF(nb) + (f0 >> 4) * XSTR + (f0 & 15) * 4) = vx0;
            *(float4*)(smem + XOFF(nb) + (f1 >> 4) * XSTR + (f1 & 15) * 4) = vx1;
            *(float4*)(smem + WOFF(nb) + (f0 >> 4) * WSTR + (f0 & 15) * 4) = vw0;
            *(float4*)(smem + WOFF(nb) + (f1 >> 4) * WSTR + (f1 & 15) * 4) = vw1;
        }
    }

    // ---- epilogue: cross-wave reduction in two 32-row halves (smem reused) ----
    const float bias = bias_v[lane];
#pragma unroll
    for (int h = 0; h < 2; ++h) {
        __syncthreads();   // h=0: compute done; h=1: previous half's reads done
#pragma unroll
        for (int ii = 0; ii < 4; ++ii) {
            const int i  = 4 * h + ii;
            const int rp = rg + 8 * i - 32 * h;     // 0..31
            float* pb = smem + wave * 2112 + rp * PSTR + eg * 8;
            *(float2*)(pb + 0) = make_float2(acc[i][0], acc[i][1]);
            *(float2*)(pb + 2) = make_float2(acc[i][2], acc[i][3]);
            *(float2*)(pb + 4) = make_float2(acc[i][4], acc[i][5]);
            *(float2*)(pb + 6) = make_float2(acc[i][6], acc[i][7]);
        }
        __syncthreads();
#pragma unroll
        for (int rr = 0; rr < 4; ++rr) {
            const int rp  = wave * 4 + rr;
            const int row = row0 + 32 * h + rp;
            float logit = bias;
#pragma unroll
            for (int p = 0; p < 8; ++p) logit += smem[p * 2112 + rp * PSTR + lane];

            float m = logit;
#pragma unroll
            for (int off = 32; off >= 1; off >>= 1)
                m = fmaxf(m, __shfl_xor(m, off));
            float ex = __expf(logit - m);
            float s = ex;
#pragma unroll
            for (int off = 32; off >= 1; off >>= 1)
                s += __shfl_xor(s, off);
            float gate = ex / s;

            float v1 = logit; int i1 = lane;
#pragma unroll
            for (int off = 32; off >= 1; off >>= 1) {
                float ov = __shfl_xor(v1, off);
                int   oi = __shfl_xor(i1, off);
                if (ov > v1 || (ov == v1 && oi < i1)) { v1 = ov; i1 = oi; }
            }
            float v2 = (lane == i1) ? -INFINITY : logit; int i2 = lane;
#pragma unroll
            for (int off = 32; off >= 1; off >>= 1) {
                float ov = __shfl_xor(v2, off);
                int   oi = __shfl_xor(i2, off);
                if (ov > v2 || (ov == v2 && oi < i2)) { v2 = ov; i2 = oi; }
            }

            float outv = (lane == i1 || lane == i2) ? gate : 0.0f;
            mask_out[(size_t)row * EEXP + lane] = outv;
            if (lane == 0) {
                idx_out[row * 2 + 0] = (float)i1;
                idx_out[row * 2 + 1] = (float)i2;
            }
        }
    }
}

extern "C" void kernel_launch(void* const* d_in, const int* in_sizes, int n_in,
                              void* d_out, int out_size, void* d_ws, size_t ws_size,
                              hipStream_t stream) {
    const float* x = (const float*)d_in[0];
    const float* W = (const float*)d_in[1];
    const float* b = (const float*)d_in[2];
    float* mask_out = (float*)d_out;
    float* idx_out  = mask_out + (size_t)NROWS * EEXP;

    dim3 grid(NROWS / RB);   // 256 blocks -> 1 block/CU, 8 waves/CU
    dim3 block(512);
    router_kernel<<<grid, block, 0, stream>>>(x, W, b, mask_out, idx_out);
}